// Round 20
// baseline (24.679 us; speedup 1.0000x reference)
//
#include <hip/hip_runtime.h>

// ThetaGammaCLEVRN — R20 = R13 with gamma-W A-frags loaded GLOBAL->REGISTER
// (no LDS round trip). Every wave consumes all 64 j of Wh as MFMA A-frags;
// the frag for (j,c,kb) is 4 pk'd W1-column pairs -> load directly into
// registers (lanes 0-15 = consecutive j -> coalesced, L2-warm). Deletes:
// Wh LDS staging (stores+swizzle in the pre-barrier chain), 8 ds_read_b128
// per lane in compute, 8 KB LDS (30.4 -> 22.4 KB). Everything else is R13
// verbatim (the 22.2 µs optimum; R14-R19 structural variants all regressed).
//
// Math (phase network dead; theta amps == 1):
//   sf = sum_o scene[e,o,:];  x = sf@(0.1*Ws)+bs  -> mfma 16x16x16 (4)
//   ga = F20(sigmoid(x)) via 257-entry LUT (computed in-block)
//   Weff[d][j] = sum_c Wq[d][c]*W1[80+c][j]       -> mfma 16x16x32
//   h = relu([W1g|Weff']@[ga;q';1]), logits=h@W2+b2, out=log_softmax
// PERMUTATION TRICK (verified R11-R13): D-layout row=16T+4kb+reg, col=lane&15;
// gamma + query k-slots permuted so MFMA outputs feed MFMA inputs directly.

typedef __fp16 h2_t  __attribute__((ext_vector_type(2)));
typedef __fp16 f16x4 __attribute__((ext_vector_type(4)));
typedef __fp16 f16x8 __attribute__((ext_vector_type(8)));
typedef float  f32x4 __attribute__((ext_vector_type(4)));
typedef unsigned u32x4 __attribute__((ext_vector_type(4)));

union H2U { unsigned u; h2_t h; };
union F4  { unsigned u[2]; f16x4 h; };
union F8  { u32x4 u; f16x8 h; };

__device__ __forceinline__ unsigned pk(float a, float b) {
    H2U v; v.h = __builtin_amdgcn_cvt_pkrtz(a, b);
    return v.u;
}
__device__ __forceinline__ float F20(float g) {
    #pragma unroll
    for (int n = 0; n < 20; ++n) {
        float g2 = g * g;
        g = fmaf(0.01f, g * (1.0f - g2), g);
    }
    return g;
}

// LDS word offsets (Wh region removed vs R13)
#define WQTo  0                    // W1qT [32 cpair][65] u32
#define WS2o  2080                 // ws2T [8][64] u32
#define LUTo  2592                 // 257 f32 (+3 pad)
#define BSo   2852                 // bs 64 f32
#define BSUMo 2916                 // b1+sum W1[0:16] 64 f32
#define W2o   2980                 // W2 128 f32
#define SFTo  3108                 // sfT [8][64] u32
#define QTo   3620                 // qT [32][66] u32 (permuted rows)
#define LDSW  (QTo + 32 * 66)      // 5732 words = 22.4 KB

__global__ __launch_bounds__(256, 4) void fused_kernel(
    const float* __restrict__ scene,   // (B,10,16)
    const float* __restrict__ query,   // (B,60)
    const float* __restrict__ Ws,      // (16,64)
    const float* __restrict__ bs,      // (64)
    const float* __restrict__ Wq,      // (60,64)
    const float* __restrict__ bq,      // (64)
    const float* __restrict__ W1,      // (144,64)
    const float* __restrict__ b1,      // (64)
    const float* __restrict__ W2,      // (64,2)
    const float* __restrict__ b2,      // (2)
    float* __restrict__ out)           // (B,2)
{
    __shared__ __align__(16) unsigned lds[LDSW];
    float* ldsF = (float*)lds;
    const int t    = threadIdx.x;
    const int lane = t & 63;
    const int wv   = __builtin_amdgcn_readfirstlane(t) >> 6;   // SGPR wave id
    const int kb   = lane >> 4;
    const int jw   = lane & 15;
    const int eb   = blockIdx.x << 6;      // 64 elements per block
    const int sel  = t >> 2, q4 = t & 3;

    // ---- Wq A-frags (registers): A[d][c], d=16dt+jw, c=32kk+8kb+i ----
    F8 aWq[4][2];
    #pragma unroll
    for (int dt = 0; dt < 4; ++dt) {
        const int d = (dt << 4) + jw;
        #pragma unroll
        for (int kk = 0; kk < 2; ++kk) {
            const int c0 = (kk << 5) + (kb << 3);
            float4 lo = {0.f,0.f,0.f,0.f}, hi = {0.f,0.f,0.f,0.f};
            if (d < 60) {
                lo = *(const float4*)(Wq + d * 64 + c0);
                hi = *(const float4*)(Wq + d * 64 + c0 + 4);
            } else if (d == 60) {          // bq rides as Wq row 60
                lo = *(const float4*)(bq + c0);
                hi = *(const float4*)(bq + c0 + 4);
            }
            F8 f;
            f.u[0] = pk(lo.x, lo.y); f.u[1] = pk(lo.z, lo.w);
            f.u[2] = pk(hi.x, hi.y); f.u[3] = pk(hi.z, hi.w);
            aWq[dt][kk] = f;
        }
    }

    // ---- stage W1qT (Wh staging DELETED — it loads to registers below) ----
    {
        const int j = lane;
        #pragma unroll
        for (int ii = 0; ii < 8; ++ii) {
            const int cp = (wv << 3) + ii;
            lds[WQTo + cp * 65 + j] =
                pk(W1[(80 + 2 * cp) * 64 + j], W1[(81 + 2 * cp) * 64 + j]);
        }
    }
    // ---- ws2T ----
    #pragma unroll
    for (int ii = 0; ii < 2; ++ii) {
        const int w = t + (ii << 8);
        const int dp = w >> 6, g = w & 63;
        lds[WS2o + w] = pk(0.1f * Ws[(2 * dp) * 64 + g],
                           0.1f * Ws[(2 * dp + 1) * 64 + g]);
    }
    // ---- LUT: F20(sigmoid(x)), x = i/32 - 4, 257 entries ----
    {
        float x0 = (float)t * 0.03125f - 4.0f;
        ldsF[LUTo + t] = F20(1.0f / (1.0f + __expf(-x0)));
        if (t == 0) ldsF[LUTo + 256] = F20(1.0f / (1.0f + __expf(-4.0f)));
    }
    // ---- bsum / bs / w2 ----
    if (t < 64) {
        float s = b1[t];
        #pragma unroll
        for (int r = 0; r < 16; ++r) s += W1[r * 64 + t];
        ldsF[BSUMo + t] = s;
    } else if (t < 128) {
        ldsF[BSo + (t - 64)] = bs[t - 64];
    } else {
        ldsF[W2o + (t - 128)] = W2[t - 128];
    }
    // ---- scene: object-sum -> sfT[8][64] ----
    {
        const float4* sp = (const float4*)scene + (size_t)(eb + sel) * 40 + q4;
        float4 a = sp[0];
        #pragma unroll
        for (int o = 1; o < 10; ++o) {
            float4 v = sp[4 * o];
            a.x += v.x; a.y += v.y; a.z += v.z; a.w += v.w;
        }
        lds[SFTo + ((q4 << 1) + 0) * 64 + sel] = pk(a.x, a.y);
        lds[SFTo + ((q4 << 1) + 1) * 64 + sel] = pk(a.z, a.w);
    }
    // ---- query -> qT[32][66], PERMUTED pair rows ----
    #pragma unroll
    for (int i = 0; i < 4; ++i) {
        const int idx = t + (i << 8);
        if (idx < 960) {
            const int qel = idx / 15, aq = idx - qel * 15;
            float4 qv = ((const float4*)query)[(size_t)(eb + qel) * 15 + aq];
            const int p0 = ((aq >> 3) << 4) + ((aq & 3) << 2) + (((aq >> 2) & 1) << 1);
            lds[QTo + (p0 + 0) * 66 + qel] = pk(qv.x, qv.y);
            lds[QTo + (p0 + 1) * 66 + qel] = pk(qv.z, qv.w);
        }
    }
    if (t < 64)       lds[QTo + 30 * 66 + t]        = pk(1.0f, 0.0f);  // d'=60
    else if (t < 128) lds[QTo + 31 * 66 + (t - 64)] = 0u;              // 62,63
    __syncthreads();

    // ============ compute: wave owns 16 elements ============
    const int q   = jw;
    const int elb = ((t >> 6) << 4) | q;

    // ---- x-MFMAs ----
    F4 bsf;
    bsf.u[0] = lds[SFTo + (2 * kb + 0) * 64 + elb];
    bsf.u[1] = lds[SFTo + (2 * kb + 1) * 64 + elb];
    f32x4 xs[4];
    #pragma unroll
    for (int tt = 0; tt < 4; ++tt) {
        F4 aW;
        aW.u[0] = lds[WS2o + (2 * kb + 0) * 64 + tt * 16 + q];
        aW.u[1] = lds[WS2o + (2 * kb + 1) * 64 + tt * 16 + q];
        f32x4 cinit = *(const f32x4*)&ldsF[BSo + tt * 16 + (kb << 2)];
        xs[tt] = __builtin_amdgcn_mfma_f32_16x16x16f16(aW.h, bsf.h, cinit, 0, 0, 0);
    }
    // ---- LUT eval + gamma B-frags ----
    auto GA = [&](float x) -> float {
        float u = fminf(fmaxf(fmaf(x, 32.0f, 128.0f), 0.0f), 255.999f);
        int   i0 = (int)u;
        float f0 = ldsF[LUTo + i0], f1 = ldsF[LUTo + i0 + 1];
        return fmaf(u - (float)i0, f1 - f0, f0);
    };
    F8 bfrag[4];
    #pragma unroll
    for (int c = 0; c < 2; ++c) {
        F8 f;
        f.u[0] = pk(GA(xs[2 * c][0]),     GA(xs[2 * c][1]));
        f.u[1] = pk(GA(xs[2 * c][2]),     GA(xs[2 * c][3]));
        f.u[2] = pk(GA(xs[2 * c + 1][0]), GA(xs[2 * c + 1][1]));
        f.u[3] = pk(GA(xs[2 * c + 1][2]), GA(xs[2 * c + 1][3]));
        bfrag[c] = f;
    }
    #pragma unroll
    for (int c2 = 0; c2 < 2; ++c2) {
        F8 f;
        #pragma unroll
        for (int r = 0; r < 4; ++r)
            f.u[r] = lds[QTo + ((kb << 2) + r + (c2 << 4)) * 66 + elb];
        bfrag[2 + c2] = f;
    }

    // ---- per j-tile: Weff via MFMA -> qA frags -> H-MFMA -> epilogue ----
    float l0 = 0.f, l1 = 0.f;
    #pragma unroll
    for (int jt = 0; jt < 4; ++jt) {
        const int j = (jt << 4) | q;

        // gamma-W A-frags straight from GLOBAL (coalesced over lanes, L2-warm)
        F8 aWh[2];
        #pragma unroll
        for (int c = 0; c < 2; ++c) {
            F8 f;
            #pragma unroll
            for (int pp = 0; pp < 4; ++pp) {
                const int p  = (((c << 2) | kb) << 2) + pp;
                const int g0 = (((p >> 4) << 1) + ((p & 3) >> 1)) * 16
                             + (((p >> 2) & 3) << 2) + ((p & 1) << 1);
                f.u[pp] = pk(W1[(16 + g0) * 64 + j], W1[(17 + g0) * 64 + j]);
            }
            aWh[c] = f;
        }

        F8 Bk[2];
        #pragma unroll
        for (int kk = 0; kk < 2; ++kk) {
            F8 f;
            #pragma unroll
            for (int r = 0; r < 4; ++r)
                f.u[r] = lds[WQTo + ((kk << 4) + (kb << 2) + r) * 65 + j];
            Bk[kk] = f;
        }
        const float bsv = ldsF[BSUMo + j];
        F8 qA[2];
        #pragma unroll
        for (int half = 0; half < 2; ++half) {
            f32x4 accT[2];
            #pragma unroll
            for (int dd = 0; dd < 2; ++dd) {
                const int dt = (half << 1) + dd;
                f32x4 c0 = {0.f, 0.f, 0.f, 0.f};
                if (dt == 3) c0[0] = (kb == 3) ? bsv : 0.f;   // d==60 row
                f32x4 a1 = __builtin_amdgcn_mfma_f32_16x16x32_f16(
                               aWq[dt][0].h, Bk[0].h, c0, 0, 0, 0);
                accT[dd] = __builtin_amdgcn_mfma_f32_16x16x32_f16(
                               aWq[dt][1].h, Bk[1].h, a1, 0, 0, 0);
            }
            F8 f;
            f.u[0] = pk(accT[0][0], accT[0][1]);
            f.u[1] = pk(accT[0][2], accT[0][3]);
            f.u[2] = pk(accT[1][0], accT[1][1]);
            f.u[3] = pk(accT[1][2], accT[1][3]);
            qA[half] = f;
        }
        f32x4 hacc = {0.f, 0.f, 0.f, 0.f};
        hacc = __builtin_amdgcn_mfma_f32_16x16x32_f16(aWh[0].h, bfrag[0].h, hacc, 0, 0, 0);
        hacc = __builtin_amdgcn_mfma_f32_16x16x32_f16(aWh[1].h, bfrag[1].h, hacc, 0, 0, 0);
        hacc = __builtin_amdgcn_mfma_f32_16x16x32_f16(qA[0].h, bfrag[2].h, hacc, 0, 0, 0);
        hacc = __builtin_amdgcn_mfma_f32_16x16x32_f16(qA[1].h, bfrag[3].h, hacc, 0, 0, 0);
        #pragma unroll
        for (int r = 0; r < 4; ++r) {
            const int jr = (jt << 4) + (kb << 2) + r;
            float hv = fmaxf(hacc[r], 0.f);
            float2 wv2 = *(const float2*)&ldsF[W2o + (jr << 1)];
            l0 = fmaf(hv, wv2.x, l0);
            l1 = fmaf(hv, wv2.y, l1);
        }
    }
    // ---- reduce over k-groups, log_softmax, store ----
    l0 += __shfl_xor(l0, 16); l0 += __shfl_xor(l0, 32);
    l1 += __shfl_xor(l1, 16); l1 += __shfl_xor(l1, 32);
    l0 += b2[0]; l1 += b2[1];
    if (lane < 16) {
        const float mx = fmaxf(l0, l1);
        const float lz = mx + __logf(__expf(l0 - mx) + __expf(l1 - mx));
        float2 o = { l0 - lz, l1 - lz };
        ((float2*)out)[eb + elb] = o;
    }
}

extern "C" void kernel_launch(void* const* d_in, const int* in_sizes, int n_in,
                              void* d_out, int out_size, void* d_ws, size_t ws_size,
                              hipStream_t stream) {
    const float* scene = (const float*)d_in[0];
    const float* query = (const float*)d_in[1];
    // d_in[2..5] = theta/gamma phase & freq: provably unused by the output
    const float* Ws = (const float*)d_in[6];
    const float* bs = (const float*)d_in[7];
    const float* Wq = (const float*)d_in[8];
    const float* bq = (const float*)d_in[9];
    const float* W1 = (const float*)d_in[10];
    const float* b1 = (const float*)d_in[11];
    const float* W2 = (const float*)d_in[12];
    const float* b2 = (const float*)d_in[13];
    float* out = (float*)d_out;

    const int B = in_sizes[0] / 160;   // 65536
    fused_kernel<<<B / 64, 256, 0, stream>>>(scene, query, Ws, bs, Wq, bq,
                                             W1, b1, W2, b2, out);
}

// Round 21
// 22.202 us; speedup vs baseline: 1.1115x; 1.1115x over previous
//
#include <hip/hip_runtime.h>

// ThetaGammaCLEVRN — FINAL = R13 exactly (measured 22.23 µs, absmax 0.0156).
// Seven structural variants (R14-R20: dbuf, 2-group, load-hoist, occupancy
// caps, 512-thread block, global-W frags) ALL regressed — R13's staging
// order + LDS layout + (256,4) + grid 1024 is the converged optimum.
//
// Math (phase network dead code — output depends only on amplitudes, the
// amplitude ODE is phase-independent, theta amps stay exactly 1):
//   sf = sum_o scene[e,o,:];  x = sf@(0.1*Ws)+bs  -> mfma 16x16x16 (4)
//   ga = F20(sigmoid(x)) via 257-entry LUT (computed in-block)
//   Weff[d][j] = sum_c Wq[d][c]*W1[80+c][j]       -> mfma 16x16x32
//   h = relu([W1g|Weff']@[ga;q';1]), logits=h@W2+b2, out=log_softmax
// PERMUTATION TRICK (verified R11-R13): D-layout row=16T+4kb+reg, col=lane&15;
// gamma + query k-slots permuted at stage so MFMA outputs feed MFMA inputs
// with zero cross-lane fixup.

typedef __fp16 h2_t  __attribute__((ext_vector_type(2)));
typedef __fp16 f16x4 __attribute__((ext_vector_type(4)));
typedef __fp16 f16x8 __attribute__((ext_vector_type(8)));
typedef float  f32x4 __attribute__((ext_vector_type(4)));
typedef unsigned u32x4 __attribute__((ext_vector_type(4)));

union H2U { unsigned u; h2_t h; };
union F4  { unsigned u[2]; f16x4 h; };
union F8  { u32x4 u; f16x8 h; };

__device__ __forceinline__ unsigned pk(float a, float b) {
    H2U v; v.h = __builtin_amdgcn_cvt_pkrtz(a, b);
    return v.u;
}
__device__ __forceinline__ float F20(float g) {
    #pragma unroll
    for (int n = 0; n < 20; ++n) {
        float g2 = g * g;
        g = fmaf(0.01f, g * (1.0f - g2), g);
    }
    return g;
}

// LDS word offsets
#define WHo   0                    // gamma Wh [64 j][32 pairs] u32, swizzled
#define WQTo  2048                 // W1qT [32 cpair][65] u32
#define WS2o  4128                 // ws2T [8][64] u32
#define LUTo  4640                 // 257 f32 (+3 pad)
#define BSo   4900                 // bs 64 f32
#define BSUMo 4964                 // b1+sum W1[0:16] 64 f32
#define W2o   5028                 // W2 128 f32
#define SFTo  5156                 // sfT [8][64] u32
#define QTo   5668                 // qT [32][66] u32 (permuted rows)
#define LDSW  (QTo + 32 * 66)      // 7780 words = 30.4 KB

__global__ __launch_bounds__(256, 4) void fused_kernel(
    const float* __restrict__ scene,   // (B,10,16)
    const float* __restrict__ query,   // (B,60)
    const float* __restrict__ Ws,      // (16,64)
    const float* __restrict__ bs,      // (64)
    const float* __restrict__ Wq,      // (60,64)
    const float* __restrict__ bq,      // (64)
    const float* __restrict__ W1,      // (144,64)
    const float* __restrict__ b1,      // (64)
    const float* __restrict__ W2,      // (64,2)
    const float* __restrict__ b2,      // (2)
    float* __restrict__ out)           // (B,2)
{
    __shared__ __align__(16) unsigned lds[LDSW];
    float* ldsF = (float*)lds;
    const int t    = threadIdx.x;
    const int lane = t & 63;
    const int wv   = __builtin_amdgcn_readfirstlane(t) >> 6;   // SGPR wave id
    const int kb   = lane >> 4;
    const int jw   = lane & 15;
    const int eb   = blockIdx.x << 6;      // 64 elements per block
    const int sel  = t >> 2, q4 = t & 3;

    // ---- Wq A-frags (registers): A[d][c], d=16dt+jw, c=32kk+8kb+i ----
    F8 aWq[4][2];
    #pragma unroll
    for (int dt = 0; dt < 4; ++dt) {
        const int d = (dt << 4) + jw;
        #pragma unroll
        for (int kk = 0; kk < 2; ++kk) {
            const int c0 = (kk << 5) + (kb << 3);
            float4 lo = {0.f,0.f,0.f,0.f}, hi = {0.f,0.f,0.f,0.f};
            if (d < 60) {
                lo = *(const float4*)(Wq + d * 64 + c0);
                hi = *(const float4*)(Wq + d * 64 + c0 + 4);
            } else if (d == 60) {          // bq rides as Wq row 60
                lo = *(const float4*)(bq + c0);
                hi = *(const float4*)(bq + c0 + 4);
            }
            F8 f;
            f.u[0] = pk(lo.x, lo.y); f.u[1] = pk(lo.z, lo.w);
            f.u[2] = pk(hi.x, hi.y); f.u[3] = pk(hi.z, hi.w);
            aWq[dt][kk] = f;
        }
    }

    // ---- stage gamma Wh (g-permuted, swizzled) + W1qT ----
    {
        const int j = lane;
        #pragma unroll
        for (int ii = 0; ii < 2; ++ii) {
            const int ch = (wv << 1) + ii;
            u32x4 v;
            #pragma unroll
            for (int pp = 0; pp < 4; ++pp) {
                const int p  = (ch << 2) + pp;
                const int g0 = (((p >> 4) << 1) + ((p & 3) >> 1)) * 16
                             + (((p >> 2) & 3) << 2) + ((p & 1) << 1);
                v[pp] = pk(W1[(16 + g0) * 64 + j], W1[(17 + g0) * 64 + j]);
            }
            *(u32x4*)&lds[WHo + (j << 5) + ((ch ^ (j & 7)) << 2)] = v;
        }
        #pragma unroll
        for (int ii = 0; ii < 8; ++ii) {
            const int cp = (wv << 3) + ii;
            lds[WQTo + cp * 65 + j] =
                pk(W1[(80 + 2 * cp) * 64 + j], W1[(81 + 2 * cp) * 64 + j]);
        }
    }
    // ---- ws2T ----
    #pragma unroll
    for (int ii = 0; ii < 2; ++ii) {
        const int w = t + (ii << 8);
        const int dp = w >> 6, g = w & 63;
        lds[WS2o + w] = pk(0.1f * Ws[(2 * dp) * 64 + g],
                           0.1f * Ws[(2 * dp + 1) * 64 + g]);
    }
    // ---- LUT: F20(sigmoid(x)), x = i/32 - 4, 257 entries ----
    {
        float x0 = (float)t * 0.03125f - 4.0f;
        ldsF[LUTo + t] = F20(1.0f / (1.0f + __expf(-x0)));
        if (t == 0) ldsF[LUTo + 256] = F20(1.0f / (1.0f + __expf(-4.0f)));
    }
    // ---- bsum / bs / w2 ----
    if (t < 64) {
        float s = b1[t];
        #pragma unroll
        for (int r = 0; r < 16; ++r) s += W1[r * 64 + t];
        ldsF[BSUMo + t] = s;
    } else if (t < 128) {
        ldsF[BSo + (t - 64)] = bs[t - 64];
    } else {
        ldsF[W2o + (t - 128)] = W2[t - 128];
    }
    // ---- scene: object-sum -> sfT[8][64] ----
    {
        const float4* sp = (const float4*)scene + (size_t)(eb + sel) * 40 + q4;
        float4 a = sp[0];
        #pragma unroll
        for (int o = 1; o < 10; ++o) {
            float4 v = sp[4 * o];
            a.x += v.x; a.y += v.y; a.z += v.z; a.w += v.w;
        }
        lds[SFTo + ((q4 << 1) + 0) * 64 + sel] = pk(a.x, a.y);
        lds[SFTo + ((q4 << 1) + 1) * 64 + sel] = pk(a.z, a.w);
    }
    // ---- query -> qT[32][66], PERMUTED pair rows ----
    #pragma unroll
    for (int i = 0; i < 4; ++i) {
        const int idx = t + (i << 8);
        if (idx < 960) {
            const int qel = idx / 15, aq = idx - qel * 15;
            float4 qv = ((const float4*)query)[(size_t)(eb + qel) * 15 + aq];
            const int p0 = ((aq >> 3) << 4) + ((aq & 3) << 2) + (((aq >> 2) & 1) << 1);
            lds[QTo + (p0 + 0) * 66 + qel] = pk(qv.x, qv.y);
            lds[QTo + (p0 + 1) * 66 + qel] = pk(qv.z, qv.w);
        }
    }
    if (t < 64)       lds[QTo + 30 * 66 + t]        = pk(1.0f, 0.0f);  // d'=60
    else if (t < 128) lds[QTo + 31 * 66 + (t - 64)] = 0u;              // 62,63
    __syncthreads();

    // ============ compute: wave owns 16 elements ============
    const int q   = jw;
    const int elb = ((t >> 6) << 4) | q;

    // ---- x-MFMAs ----
    F4 bsf;
    bsf.u[0] = lds[SFTo + (2 * kb + 0) * 64 + elb];
    bsf.u[1] = lds[SFTo + (2 * kb + 1) * 64 + elb];
    f32x4 xs[4];
    #pragma unroll
    for (int tt = 0; tt < 4; ++tt) {
        F4 aW;
        aW.u[0] = lds[WS2o + (2 * kb + 0) * 64 + tt * 16 + q];
        aW.u[1] = lds[WS2o + (2 * kb + 1) * 64 + tt * 16 + q];
        f32x4 cinit = *(const f32x4*)&ldsF[BSo + tt * 16 + (kb << 2)];
        xs[tt] = __builtin_amdgcn_mfma_f32_16x16x16f16(aW.h, bsf.h, cinit, 0, 0, 0);
    }
    // ---- LUT eval + gamma B-frags ----
    auto GA = [&](float x) -> float {
        float u = fminf(fmaxf(fmaf(x, 32.0f, 128.0f), 0.0f), 255.999f);
        int   i0 = (int)u;
        float f0 = ldsF[LUTo + i0], f1 = ldsF[LUTo + i0 + 1];
        return fmaf(u - (float)i0, f1 - f0, f0);
    };
    F8 bfrag[4];
    #pragma unroll
    for (int c = 0; c < 2; ++c) {
        F8 f;
        f.u[0] = pk(GA(xs[2 * c][0]),     GA(xs[2 * c][1]));
        f.u[1] = pk(GA(xs[2 * c][2]),     GA(xs[2 * c][3]));
        f.u[2] = pk(GA(xs[2 * c + 1][0]), GA(xs[2 * c + 1][1]));
        f.u[3] = pk(GA(xs[2 * c + 1][2]), GA(xs[2 * c + 1][3]));
        bfrag[c] = f;
    }
    #pragma unroll
    for (int c2 = 0; c2 < 2; ++c2) {
        F8 f;
        #pragma unroll
        for (int r = 0; r < 4; ++r)
            f.u[r] = lds[QTo + ((kb << 2) + r + (c2 << 4)) * 66 + elb];
        bfrag[2 + c2] = f;
    }

    // ---- per j-tile: Weff via MFMA -> qA frags -> H-MFMA -> epilogue ----
    float l0 = 0.f, l1 = 0.f;
    #pragma unroll
    for (int jt = 0; jt < 4; ++jt) {
        const int j = (jt << 4) | q;
        F8 Bk[2];
        #pragma unroll
        for (int kk = 0; kk < 2; ++kk) {
            F8 f;
            #pragma unroll
            for (int r = 0; r < 4; ++r)
                f.u[r] = lds[WQTo + ((kk << 4) + (kb << 2) + r) * 65 + j];
            Bk[kk] = f;
        }
        const float bsv = ldsF[BSUMo + j];
        F8 qA[2];
        #pragma unroll
        for (int half = 0; half < 2; ++half) {
            f32x4 accT[2];
            #pragma unroll
            for (int dd = 0; dd < 2; ++dd) {
                const int dt = (half << 1) + dd;
                f32x4 c0 = {0.f, 0.f, 0.f, 0.f};
                if (dt == 3) c0[0] = (kb == 3) ? bsv : 0.f;   // d==60 row
                f32x4 a1 = __builtin_amdgcn_mfma_f32_16x16x32_f16(
                               aWq[dt][0].h, Bk[0].h, c0, 0, 0, 0);
                accT[dd] = __builtin_amdgcn_mfma_f32_16x16x32_f16(
                               aWq[dt][1].h, Bk[1].h, a1, 0, 0, 0);
            }
            F8 f;
            f.u[0] = pk(accT[0][0], accT[0][1]);
            f.u[1] = pk(accT[0][2], accT[0][3]);
            f.u[2] = pk(accT[1][0], accT[1][1]);
            f.u[3] = pk(accT[1][2], accT[1][3]);
            qA[half] = f;
        }
        f32x4 hacc = {0.f, 0.f, 0.f, 0.f};
        #pragma unroll
        for (int c = 0; c < 2; ++c) {
            const int ch = ((c << 2) | kb) ^ (j & 7);
            F8 a;
            a.u = *(const u32x4*)&lds[WHo + (j << 5) + (ch << 2)];
            hacc = __builtin_amdgcn_mfma_f32_16x16x32_f16(a.h, bfrag[c].h, hacc, 0, 0, 0);
        }
        hacc = __builtin_amdgcn_mfma_f32_16x16x32_f16(qA[0].h, bfrag[2].h, hacc, 0, 0, 0);
        hacc = __builtin_amdgcn_mfma_f32_16x16x32_f16(qA[1].h, bfrag[3].h, hacc, 0, 0, 0);
        #pragma unroll
        for (int r = 0; r < 4; ++r) {
            const int jr = (jt << 4) + (kb << 2) + r;
            float hv = fmaxf(hacc[r], 0.f);
            float2 wv2 = *(const float2*)&ldsF[W2o + (jr << 1)];
            l0 = fmaf(hv, wv2.x, l0);
            l1 = fmaf(hv, wv2.y, l1);
        }
    }
    // ---- reduce over k-groups, log_softmax, store ----
    l0 += __shfl_xor(l0, 16); l0 += __shfl_xor(l0, 32);
    l1 += __shfl_xor(l1, 16); l1 += __shfl_xor(l1, 32);
    l0 += b2[0]; l1 += b2[1];
    if (lane < 16) {
        const float mx = fmaxf(l0, l1);
        const float lz = mx + __logf(__expf(l0 - mx) + __expf(l1 - mx));
        float2 o = { l0 - lz, l1 - lz };
        ((float2*)out)[eb + elb] = o;
    }
}

extern "C" void kernel_launch(void* const* d_in, const int* in_sizes, int n_in,
                              void* d_out, int out_size, void* d_ws, size_t ws_size,
                              hipStream_t stream) {
    const float* scene = (const float*)d_in[0];
    const float* query = (const float*)d_in[1];
    // d_in[2..5] = theta/gamma phase & freq: provably unused by the output
    const float* Ws = (const float*)d_in[6];
    const float* bs = (const float*)d_in[7];
    const float* Wq = (const float*)d_in[8];
    const float* bq = (const float*)d_in[9];
    const float* W1 = (const float*)d_in[10];
    const float* b1 = (const float*)d_in[11];
    const float* W2 = (const float*)d_in[12];
    const float* b2 = (const float*)d_in[13];
    float* out = (float*)d_out;

    const int B = in_sizes[0] / 160;   // 65536
    fused_kernel<<<B / 64, 256, 0, stream>>>(scene, query, Ws, bs, Wq, bq,
                                             W1, b1, W2, b2, out);
}